// Round 2
// baseline (4516.232 us; speedup 1.0000x reference)
//
#include <hip/hip_runtime.h>

typedef _Float16 f16;
typedef _Float16 f16x8 __attribute__((ext_vector_type(8)));
typedef float f32x4 __attribute__((ext_vector_type(4)));

#define B_ 128
#define T_ 512
#define H_ 192
#define G3 576
#define NX 1152

// ---- workspace layout (bytes). Total 204,718,080 < 256 MiB. ----
// [0, 150994944)                    gxb   : gx gate pre-acts, f16 [t*128+b][1152]
// [150994944, 201326592)            hbuf  : layer h output, f16 [b][t][384]
//                                           (in0 f16 [b][t][128] aliases its first 16.8MB)
// [201326592, 203390976)            wihf  : f16 w_ih (L0 147456, L1 442368, L2 442368)
// [203390976, 204718080)            whhf  : f16 w_hh (3 x 221184)
#define OFF_H   150994944u
#define OFF_WIH 201326592u
#define OFF_WHH 203390976u

__device__ __forceinline__ void gload_lds16(const void* g, void* l) {
  __builtin_amdgcn_global_load_lds(
      (const __attribute__((address_space(1))) unsigned int*)g,
      (__attribute__((address_space(3))) unsigned int*)l, 16, 0, 0);
}

__device__ __forceinline__ float sigm(float x) {
  return __fdividef(1.f, 1.f + __expf(-x));
}
__device__ __forceinline__ float tanhf_(float x) {
  float ax = fabsf(x);
  float e = __expf(-2.f * ax);
  float t = __fdividef(1.f - e, 1.f + e);
  return copysignf(t, x);
}

// ---------------- weight f32 -> f16 conversion ----------------
__global__ void wconv_kernel(const float* __restrict__ s0, const float* __restrict__ h0,
                             const float* __restrict__ s1, const float* __restrict__ h1,
                             const float* __restrict__ s2, const float* __restrict__ h2,
                             f16* __restrict__ wih, f16* __restrict__ whh) {
  const int stride = gridDim.x * blockDim.x;
  for (int i = blockIdx.x * blockDim.x + threadIdx.x; i < 1695744; i += stride) {
    if (i < 1032192) {
      f16 v;
      if (i < 147456) v = (f16)s0[i];
      else if (i < 589824) v = (f16)s1[i - 147456];
      else v = (f16)s2[i - 589824];
      wih[i] = v;
    } else {
      int j = i - 1032192;
      f16 v;
      if (j < 221184) v = (f16)h0[j];
      else if (j < 442368) v = (f16)h1[j - 221184];
      else v = (f16)h2[j - 442368];
      whh[j] = v;
    }
  }
}

// ---------------- embedding gather -> f16 ----------------
__global__ void embed_kernel(const int* __restrict__ x, const float* __restrict__ emb,
                             f16* __restrict__ o) {
  const int row = (blockIdx.x << 2) + (threadIdx.x >> 6);  // b*512+t
  const int lane = threadIdx.x & 63;
  const int idx = x[row];
  const float2 v = *(const float2*)(emb + ((size_t)idx << 7) + (lane << 1));
  union { f16 h[2]; unsigned u; } p;
  p.h[0] = (f16)v.x;
  p.h[1] = (f16)v.y;
  *(unsigned*)(o + ((size_t)row << 7) + (lane << 1)) = p.u;
}

// ---------------- gx = X @ w_ih^T + b_ih (f16 MFMA GEMM) ----------------
// A: [128][512][DIN] f16 (b,t,k).  W: [1152][DIN] f16 (d*576+j, k).  gxo: [t*128+b][1152] f16.
template <int DIN>
__global__ __launch_bounds__(256) void gx_gemm(const f16* __restrict__ A,
                                               const f16* __restrict__ W,
                                               const float* __restrict__ bih,
                                               f16* __restrict__ gxo) {
  const int t = blockIdx.x;        // M-tile: all 128 b at this t
  const int nt0 = blockIdx.y << 7; // N-tile base (128 wide)
  const int tid = threadIdx.x;
  const int lane = tid & 63;
  const int w = tid >> 6;
  const int l16 = lane & 15;
  const int lq = lane >> 4;
  const int wm = (w >> 1) << 6;
  const int wn = (w & 1) << 6;

  __shared__ __align__(16) f16 Al[128 * 128];
  __shared__ __align__(16) f16 Bl[128 * 128];

  f32x4 acc[4][4] = {};

  const int srow = tid >> 4;  // staging row-within-16
  const int sc = tid & 15;    // staging phys chunk

  for (int kk = 0; kk < DIN; kk += 128) {
    __syncthreads();
    // stage A-tile [128 rows][128 k] and B-tile [128 n-rows][128 k], 16B/lane,
    // linear LDS dest + XOR-preswizzled global source chunk (cl = c ^ (row&7))
#pragma unroll
    for (int it = 0; it < 8; ++it) {
      const int r = (it << 4) + srow;
      const int cl = sc ^ (r & 7);
      gload_lds16(A + (size_t)(r * T_ + t) * DIN + kk + cl * 8, Al + (it << 11) + tid * 8);
      const int n = nt0 + r;
      gload_lds16(W + (size_t)n * DIN + kk + cl * 8, Bl + (it << 11) + tid * 8);
    }
    __syncthreads();
#pragma unroll
    for (int kt = 0; kt < 4; ++kt) {
      f16x8 af[4], bf[4];
#pragma unroll
      for (int mt = 0; mt < 4; ++mt) {
        const int r = wm + (mt << 4) + l16;
        const int c = ((kt << 2) + lq) ^ (r & 7);
        af[mt] = *(const f16x8*)(Al + (r << 7) + (c << 3));
      }
#pragma unroll
      for (int nt = 0; nt < 4; ++nt) {
        const int r = wn + (nt << 4) + l16;
        const int c = ((kt << 2) + lq) ^ (r & 7);
        bf[nt] = *(const f16x8*)(Bl + (r << 7) + (c << 3));
      }
#pragma unroll
      for (int mt = 0; mt < 4; ++mt)
#pragma unroll
        for (int nt = 0; nt < 4; ++nt)
          acc[mt][nt] = __builtin_amdgcn_mfma_f32_16x16x32_f16(af[mt], bf[nt], acc[mt][nt], 0, 0, 0);
    }
  }
  // epilogue: + b_ih, store f16.  C layout: row = lq*4+i, col = l16 (m89-verified).
#pragma unroll
  for (int nt = 0; nt < 4; ++nt) {
    const int n = nt0 + wn + (nt << 4) + l16;
    const float bias = bih[n];
#pragma unroll
    for (int mt = 0; mt < 4; ++mt) {
#pragma unroll
      for (int i = 0; i < 4; ++i) {
        const int m = (t << 7) + wm + (mt << 4) + (lq << 2) + i;
        gxo[(size_t)m * NX + n] = (f16)(acc[mt][nt][i] + bias);
      }
    }
  }
}

// ---------------- recurrent scan ----------------
// 16 workgroups: (8 batch-blocks of 16 rows) x (2 dirs).  4 waves; wave w owns
// h-cols [48w,48w+48) = 3 col-tiles q, and n-tiles {s*192 + w*48 + q*16} for s=r,z,n.
// w_hh fragments live in VGPRs for the whole scan.  h state f32 in registers.
__global__ __launch_bounds__(256, 1) void gru_scan(const f16* __restrict__ gx,
                                                   const f16* __restrict__ whh,
                                                   const float* __restrict__ bhh,
                                                   f16* __restrict__ out,
                                                   int last) {
  const int bx = blockIdx.x;
  const int d = bx & 1;
  const int b0 = (bx >> 1) << 4;
  const int tid = threadIdx.x;
  const int lane = tid & 63;
  const int w = tid >> 6;
  const int l16 = lane & 15;
  const int lq = lane >> 4;

  // h tile as next-step A-fragments; 200-f16 row stride (400B) -> 2-way banks only
  __shared__ __align__(16) f16 hl[2][16][200];
  for (int i = tid; i < 2 * 16 * 200; i += 256) ((f16*)hl)[i] = (f16)0.f;

  const f16* whd = whh + (size_t)d * (G3 * H_);
  f16x8 wf[3][3][6];
#pragma unroll
  for (int s = 0; s < 3; ++s)
#pragma unroll
    for (int q = 0; q < 3; ++q) {
      const int nrow = s * 192 + w * 48 + q * 16 + l16;
#pragma unroll
      for (int kt = 0; kt < 6; ++kt)
        wf[s][q][kt] = *(const f16x8*)(whd + (size_t)nrow * H_ + kt * 32 + lq * 8);
    }
  float bh[3][3];
#pragma unroll
  for (int s = 0; s < 3; ++s)
#pragma unroll
    for (int q = 0; q < 3; ++q)
      bh[s][q] = bhh[d * G3 + s * 192 + w * 48 + q * 16 + l16];

  float hreg[3][4];
#pragma unroll
  for (int q = 0; q < 3; ++q)
#pragma unroll
    for (int i = 0; i < 4; ++i) hreg[q][i] = 0.f;

  const int nsteps = (last && d == 1) ? 1 : T_;
  const bool fwd = (d == 0);
  __syncthreads();

  int buf = 0;
  for (int step = 0; step < nsteps; ++step) {
    const int t = fwd ? step : (T_ - 1 - step);

    // gx loads: issued first (no deps) so HBM latency hides under LDS reads + MFMAs
    float ga[3][3][4];
    const f16* gp = gx + (size_t)(t * B_ + b0 + (lq << 2)) * NX + d * G3 + w * 48 + l16;
#pragma unroll
    for (int s = 0; s < 3; ++s)
#pragma unroll
      for (int q = 0; q < 3; ++q)
#pragma unroll
        for (int i = 0; i < 4; ++i)
          ga[s][q][i] = (float)gp[(size_t)i * NX + s * 192 + q * 16];

    // gh = h @ w_hh^T  (+ b_hh folded into acc init)
    f32x4 acc[3][3];
#pragma unroll
    for (int s = 0; s < 3; ++s)
#pragma unroll
      for (int q = 0; q < 3; ++q) {
        const float bv = bh[s][q];
        acc[s][q] = (f32x4){bv, bv, bv, bv};
      }
#pragma unroll
    for (int kt = 0; kt < 6; ++kt) {
      // A-fragment of h (row = l16, k = kt*32 + lq*8 + e); one frag live at a time
      const f16x8 af = *(const f16x8*)(&hl[buf][l16][kt * 32 + lq * 8]);
#pragma unroll
      for (int s = 0; s < 3; ++s)
#pragma unroll
        for (int q = 0; q < 3; ++q)
          acc[s][q] = __builtin_amdgcn_mfma_f32_16x16x32_f16(af, wf[s][q][kt], acc[s][q], 0, 0, 0);
    }

    // gates + state update (lane-local, f32)
    const bool wr = (!last) || (t == T_ - 1);
#pragma unroll
    for (int q = 0; q < 3; ++q)
#pragma unroll
      for (int i = 0; i < 4; ++i) {
        const float r = sigm(ga[0][q][i] + acc[0][q][i]);
        const float z = sigm(ga[1][q][i] + acc[1][q][i]);
        const float n = tanhf_(ga[2][q][i] + r * acc[2][q][i]);
        const float h = n + z * (hreg[q][i] - n);
        hreg[q][i] = h;
        hl[buf ^ 1][(lq << 2) + i][w * 48 + q * 16 + l16] = (f16)h;
        if (wr)
          out[((size_t)(b0 + (lq << 2) + i) * T_ + t) * 384 + d * H_ + w * 48 + q * 16 + l16] = (f16)h;
      }
    __syncthreads();
    buf ^= 1;
  }
}

// ---------------- FC head ----------------
__global__ void fc_kernel(const f16* __restrict__ h2, const float* __restrict__ w1,
                          const float* __restrict__ b1, const float* __restrict__ w2,
                          const float* __restrict__ b2, float* __restrict__ y) {
  const int b = blockIdx.x;
  const int i = threadIdx.x;  // 128 threads = fc1 units
  __shared__ float hs[384];
  __shared__ float us[128];
  const f16* hp = h2 + ((size_t)b * T_ + (T_ - 1)) * 384;
  for (int k = i; k < 384; k += 128) hs[k] = (float)hp[k];
  __syncthreads();
  float a = b1[i];
  for (int k = 0; k < 384; ++k) a = fmaf(w1[i * 384 + k], hs[k], a);
  us[i] = fmaxf(a, 0.f) * w2[i];
  __syncthreads();
  if (i == 0) {
    float s = b2[0];
    for (int k = 0; k < 128; ++k) s += us[k];
    y[b] = s;
  }
}

extern "C" void kernel_launch(void* const* d_in, const int* in_sizes, int n_in,
                              void* d_out, int out_size, void* d_ws, size_t ws_size,
                              hipStream_t stream) {
  const int* x = (const int*)d_in[0];
  const float* emb = (const float*)d_in[1];
  const float* wih[3] = {(const float*)d_in[2], (const float*)d_in[6], (const float*)d_in[10]};
  const float* whh[3] = {(const float*)d_in[3], (const float*)d_in[7], (const float*)d_in[11]};
  const float* bih[3] = {(const float*)d_in[4], (const float*)d_in[8], (const float*)d_in[12]};
  const float* bhh[3] = {(const float*)d_in[5], (const float*)d_in[9], (const float*)d_in[13]};
  const float* fc1w = (const float*)d_in[14];
  const float* fc1b = (const float*)d_in[15];
  const float* fc2w = (const float*)d_in[16];
  const float* fc2b = (const float*)d_in[17];
  float* y = (float*)d_out;

  char* ws = (char*)d_ws;
  f16* gxb = (f16*)(ws);             // 150,994,944 B
  f16* hbuf = (f16*)(ws + OFF_H);    // 50,331,648 B (single h buffer for all layers)
  f16* in0 = hbuf;                   // embedding output aliases hbuf start (dead after gemm0)
  f16* wihf = (f16*)(ws + OFF_WIH);
  f16* whhf = (f16*)(ws + OFF_WHH);

  wconv_kernel<<<1024, 256, 0, stream>>>(wih[0], whh[0], wih[1], whh[1], wih[2], whh[2], wihf, whhf);
  embed_kernel<<<16384, 256, 0, stream>>>(x, emb, in0);

  // layer 0
  gx_gemm<128><<<dim3(512, 9), 256, 0, stream>>>(in0, wihf, bih[0], gxb);
  gru_scan<<<16, 256, 0, stream>>>(gxb, whhf, bhh[0], hbuf, 0);
  // layer 1
  gx_gemm<384><<<dim3(512, 9), 256, 0, stream>>>(hbuf, wihf + 147456, bih[1], gxb);
  gru_scan<<<16, 256, 0, stream>>>(gxb, whhf + 221184, bhh[1], hbuf, 0);
  // layer 2 (bwd dir needs only 1 step; fwd writes only t=511)
  gx_gemm<384><<<dim3(512, 9), 256, 0, stream>>>(hbuf, wihf + 147456 + 442368, bih[2], gxb);
  gru_scan<<<16, 256, 0, stream>>>(gxb, whhf + 2 * 221184, bhh[2], hbuf, 1);

  fc_kernel<<<128, 128, 0, stream>>>(hbuf, fc1w, fc1b, fc2w, fc2b, y);
}